// Round 16
// baseline (215.792 us; speedup 1.0000x reference)
//
#include <hip/hip_runtime.h>
#include <hip/hip_bf16.h>

#define NN   100000
#define NE   50000
#define NNZP 1600000
#define DD   128

#define EBK  512
#define NBE  ((NE + EBK - 1) / EBK)             // 98
#define VBK  512
#define NBV  ((NN + VBK - 1) / VBK)             // 196
#define NBT  (NBE + NBV)                        // 294
#define CH2  3200                               // pairs per scatter block
#define NSB  500                                // 500 * 3200 == NNZP
#define NGB  ((NN / 16 + 7) / 8)                // 782 gemm blocks

typedef __attribute__((ext_vector_type(8))) short bf16x8;
typedef __attribute__((ext_vector_type(4))) float f32x4;
typedef __attribute__((ext_vector_type(4))) unsigned int u32x4;

__device__ __forceinline__ ushort f2bf(float f) {
    __hip_bfloat16 h = __float2bfloat16(f);
    return *reinterpret_cast<ushort*>(&h);
}
// accumulate 8 bf16 (one 16B load) into a[0..8)
__device__ __forceinline__ void accQ(u32x4 u, float* a) {
    a[0] += __uint_as_float(u.x << 16);
    a[1] += __uint_as_float(u.x & 0xffff0000u);
    a[2] += __uint_as_float(u.y << 16);
    a[3] += __uint_as_float(u.y & 0xffff0000u);
    a[4] += __uint_as_float(u.z << 16);
    a[5] += __uint_as_float(u.z & 0xffff0000u);
    a[6] += __uint_as_float(u.w << 16);
    a[7] += __uint_as_float(u.w & 0xffff0000u);
}
__device__ __forceinline__ u32x4 ldg_u4(const ushort* p) {
    return *reinterpret_cast<const u32x4*>(p);
}

// exclusive scan of gCnt[0..NBT) into sbase (LDS); 256 threads, 2 elems/thread
__device__ __forceinline__ void scan_gcnt(const int* __restrict__ gCnt,
                                          int* sbase, int* wsum) {
    const int t = threadIdx.x;
    int c0 = (2 * t     < NBT) ? gCnt[2 * t]     : 0;
    int c1 = (2 * t + 1 < NBT) ? gCnt[2 * t + 1] : 0;
    int s = c0 + c1;
    int inc = s;
    #pragma unroll
    for (int d = 1; d < 64; d <<= 1) {
        int x = __shfl_up(inc, d, 64);
        if ((t & 63) >= d) inc += x;
    }
    if ((t & 63) == 63) wsum[t >> 6] = inc;
    __syncthreads();
    int wid = t >> 6, wbase = 0;
    #pragma unroll
    for (int w = 0; w < 3; ++w) if (w < wid) wbase += wsum[w];
    int excl = wbase + inc - s;
    if (2 * t     < NBT) sbase[2 * t]     = excl;
    if (2 * t + 1 < NBT) sbase[2 * t + 1] = excl + c0;
    __syncthreads();
}

// per-bucket placement body: hist run -> LDS scan -> write offs -> place payloads
__device__ __forceinline__ void place_bucket_body(const unsigned int* __restrict__ buck,
                                                  int id0, int nid, int start, int end,
                                                  int sh_amt, unsigned msk,
                                                  int* __restrict__ off,
                                                  int* __restrict__ lst,
                                                  int* cnt, int* wsum) {
    const int t = threadIdx.x;
    for (int i = t; i < nid; i += 256) cnt[i] = 0;
    __syncthreads();
    for (int i = start + t; i < end; i += 256)
        atomicAdd(&cnt[buck[i] >> sh_amt], 1);
    __syncthreads();
    int c0 = (2 * t     < nid) ? cnt[2 * t]     : 0;
    int c1 = (2 * t + 1 < nid) ? cnt[2 * t + 1] : 0;
    int s = c0 + c1;
    int inc = s;
    #pragma unroll
    for (int d = 1; d < 64; d <<= 1) {
        int x = __shfl_up(inc, d, 64);
        if ((t & 63) >= d) inc += x;
    }
    if ((t & 63) == 63) wsum[t >> 6] = inc;
    __syncthreads();
    int wid = t >> 6, wbase = 0;
    #pragma unroll
    for (int w = 0; w < 3; ++w) if (w < wid) wbase += wsum[w];
    int excl = start + wbase + (inc - s);
    if (2 * t     < nid) off[id0 + 2 * t]     = excl;
    if (2 * t + 1 < nid) off[id0 + 2 * t + 1] = excl + c0;
    __syncthreads();
    if (2 * t     < nid) cnt[2 * t]     = excl;
    if (2 * t + 1 < nid) cnt[2 * t + 1] = excl + c0;
    __syncthreads();
    for (int i = start + t; i < end; i += 256) {
        unsigned p = buck[i];
        lst[atomicAdd(&cnt[p >> sh_amt], 1)] = (int)(p & msk);
    }
}

// ------- K1: per-(bucket,block) counts, no global atomics; + Wt convert tail -------
__global__ __launch_bounds__(256) void scatter_count(const int* __restrict__ vertex,
                                                     const int* __restrict__ edges,
                                                     int* __restrict__ blkCnt,
                                                     const float* __restrict__ W,
                                                     ushort* __restrict__ Wt) {
    __shared__ int c[NBT];
    const int t = threadIdx.x;
    if (blockIdx.x >= NSB) {        // tail: Wt16[n][k] = bf16(W[k][n])
        int i = (blockIdx.x - NSB) * 256 + t;
        if (i < DD * DD) { int k = i >> 7, n = i & 127; Wt[n * DD + k] = f2bf(W[i]); }
        return;
    }
    for (int i = t; i < NBT; i += 256) c[i] = 0;
    __syncthreads();
    const int base = blockIdx.x * CH2;
    for (int i = t; i < CH2 / 4; i += 256) {
        int4 e4 = *reinterpret_cast<const int4*>(edges + base + i * 4);
        int4 v4 = *reinterpret_cast<const int4*>(vertex + base + i * 4);
        atomicAdd(&c[e4.x >> 9], 1); atomicAdd(&c[e4.y >> 9], 1);
        atomicAdd(&c[e4.z >> 9], 1); atomicAdd(&c[e4.w >> 9], 1);
        atomicAdd(&c[NBE + (v4.x >> 9)], 1); atomicAdd(&c[NBE + (v4.y >> 9)], 1);
        atomicAdd(&c[NBE + (v4.z >> 9)], 1); atomicAdd(&c[NBE + (v4.w >> 9)], 1);
    }
    __syncthreads();
    for (int i = t; i < NBT; i += 256) blkCnt[i * NSB + blockIdx.x] = c[i];
}

// ------- K2: per-bucket scan of 500 block counts -> relative offsets; total -> gCnt;
//             also writes the fixed CSR tails -------
__global__ __launch_bounds__(256) void blk_scan(int* __restrict__ blkCnt,
                                                int* __restrict__ gCnt,
                                                int* __restrict__ eoff,
                                                int* __restrict__ voff) {
    __shared__ int wsum[4];
    const int t = threadIdx.x;
    if (blockIdx.x == 0 && t == 0) { eoff[NE] = NNZP; voff[NN] = NNZP; }
    int* p = blkCnt + blockIdx.x * NSB;
    int c0 = (2 * t     < NSB) ? p[2 * t]     : 0;
    int c1 = (2 * t + 1 < NSB) ? p[2 * t + 1] : 0;
    int s = c0 + c1;
    int inc = s;
    #pragma unroll
    for (int d = 1; d < 64; d <<= 1) {
        int x = __shfl_up(inc, d, 64);
        if ((t & 63) >= d) inc += x;
    }
    if ((t & 63) == 63) wsum[t >> 6] = inc;
    __syncthreads();
    int wid = t >> 6, wbase = 0;
    #pragma unroll
    for (int w = 0; w < 3; ++w) if (w < wid) wbase += wsum[w];
    int excl = wbase + inc - s;
    if (2 * t     < NSB) p[2 * t]     = excl;
    if (2 * t + 1 < NSB) p[2 * t + 1] = excl + c0;
    if (t == 255) gCnt[blockIdx.x] = wbase + inc;   // bucket total
}

// ------- K3 (fused): blocks [0,NGB) = MFMA GEMM; blocks [NGB,NGB+NSB) = placement ----
// ebuckP[i] = (e&511)<<17 | v ; vbuckP[i] = (v&511)<<16 | e
__global__ __launch_bounds__(256) void place_gemm(const int* __restrict__ vertex,
                                                  const int* __restrict__ edges,
                                                  const int* __restrict__ blkCnt,
                                                  const int* __restrict__ gCnt,
                                                  unsigned int* __restrict__ ebuckP,
                                                  unsigned int* __restrict__ vbuckP,
                                                  const float* __restrict__ X,
                                                  const ushort* __restrict__ Wt,
                                                  ushort* __restrict__ Xp16) {
    __shared__ char smem[DD * DD * 2];   // 32 KB: WtL (gemm) | sbase+cur (placement)
    __shared__ int wsum[4];
    const int t = threadIdx.x;
    if (blockIdx.x < NGB) {
        // ------- GEMM: Xp16 = bf16( X @ W ), 2 rowTiles/wave; Wt16 staged coalesced ----
        char* WtL = smem;
        for (int c = t; c < 2048; c += 256) {
            int n = c >> 4, kc = c & 15;
            int dst = (n * 256 + kc * 16) ^ ((n & 7) << 4);
            *reinterpret_cast<int4*>(WtL + dst) = reinterpret_cast<const int4*>(Wt)[c];
        }
        __syncthreads();
        int wave = t >> 6;
        int lane = t & 63;
        int r = lane & 15, half = lane >> 4;
        #pragma unroll
        for (int rt = 0; rt < 2; ++rt) {
            int rowTile = blockIdx.x * 8 + wave * 2 + rt;
            if (rowTile >= NN / 16) break;
            const float* xrow = X + (size_t)(rowTile * 16 + r) * DD;
            f32x4 acc[8];
            #pragma unroll
            for (int nt = 0; nt < 8; ++nt) acc[nt] = (f32x4)(0.f);
            #pragma unroll
            for (int kk = 0; kk < DD; kk += 32) {
                int kbase = kk + half * 8;
                float4 xa = *reinterpret_cast<const float4*>(xrow + kbase);
                float4 xb = *reinterpret_cast<const float4*>(xrow + kbase + 4);
                bf16x8 a;
                a[0] = (short)f2bf(xa.x); a[1] = (short)f2bf(xa.y);
                a[2] = (short)f2bf(xa.z); a[3] = (short)f2bf(xa.w);
                a[4] = (short)f2bf(xb.x); a[5] = (short)f2bf(xb.y);
                a[6] = (short)f2bf(xb.z); a[7] = (short)f2bf(xb.w);
                #pragma unroll
                for (int nt = 0; nt < 8; ++nt) {
                    int n = nt * 16 + r;
                    int off = (n * 256 + kbase * 2) ^ ((n & 7) << 4);
                    bf16x8 b = *reinterpret_cast<const bf16x8*>(WtL + off);
                    acc[nt] = __builtin_amdgcn_mfma_f32_16x16x32_bf16(a, b, acc[nt], 0, 0, 0);
                }
            }
            int row0 = rowTile * 16 + half * 4;   // C/D: col=lane&15, row=(lane>>4)*4+q
            #pragma unroll
            for (int nt = 0; nt < 8; ++nt)
                #pragma unroll
                for (int q = 0; q < 4; ++q)
                    Xp16[(size_t)(row0 + q) * DD + nt * 16 + r] = f2bf(acc[nt][q]);
        }
    } else {
        // ---------------- placement with deterministic cursors ----------------
        const int pb = blockIdx.x - NGB;          // 0..NSB-1
        int* sbase = reinterpret_cast<int*>(smem);       // NBT
        int* cur   = sbase + NBT;                        // NBT
        scan_gcnt(gCnt, sbase, wsum);
        for (int i = t; i < NBT; i += 256) {
            int rel = blkCnt[i * NSB + pb];
            int b = sbase[i] - ((i < NBE) ? 0 : NNZP);
            cur[i] = b + rel;
        }
        __syncthreads();
        const int base = pb * CH2;
        for (int i = t; i < CH2 / 2; i += 256) {
            int2 e2 = *reinterpret_cast<const int2*>(edges + base + i * 2);
            int2 v2 = *reinterpret_cast<const int2*>(vertex + base + i * 2);
            int pe0 = atomicAdd(&cur[e2.x >> 9], 1);
            ebuckP[pe0] = ((unsigned)(e2.x & 511) << 17) | (unsigned)v2.x;
            int pe1 = atomicAdd(&cur[e2.y >> 9], 1);
            ebuckP[pe1] = ((unsigned)(e2.y & 511) << 17) | (unsigned)v2.y;
            int pv0 = atomicAdd(&cur[NBE + (v2.x >> 9)], 1);
            vbuckP[pv0] = ((unsigned)(v2.x & 511) << 16) | (unsigned)e2.x;
            int pv1 = atomicAdd(&cur[NBE + (v2.y >> 9)], 1);
            vbuckP[pv1] = ((unsigned)(v2.y & 511) << 16) | (unsigned)e2.y;
        }
    }
}

// ------- K4: edge buckets only: hist + scan -> eoff, place vlist -------
__global__ __launch_bounds__(256) void place_buckets_e(const unsigned int* __restrict__ ebuckP,
                                                       const int* __restrict__ gCnt,
                                                       int* __restrict__ eoff,
                                                       int* __restrict__ vlist) {
    __shared__ int sbase[NBT];
    __shared__ int cnt[EBK];
    __shared__ int wsum[4];
    scan_gcnt(gCnt, sbase, wsum);
    int b = blockIdx.x;                          // < NBE
    int id0 = b * EBK, nid = min(EBK, NE - id0);
    int start = sbase[b], end = start + gCnt[b];
    place_bucket_body(ebuckP, id0, nid, start, end, 17, 0x1FFFFu, eoff, vlist, cnt, wsum);
}

// ---- K5 (fused): blocks [0,NBV) = vertex-bucket placement (voff/elist);
//                  blocks [NBV, NBV + NE/16) = edge gather ----
__global__ __launch_bounds__(256) void edge_gather_pbv(const ushort* __restrict__ Xp16,
                                                       const int* __restrict__ eoff,
                                                       const int* __restrict__ vlist,
                                                       float* __restrict__ Xe,
                                                       ushort* __restrict__ Xe16,
                                                       const unsigned int* __restrict__ vbuckP,
                                                       const int* __restrict__ gCnt,
                                                       int* __restrict__ voff,
                                                       int* __restrict__ elist) {
    __shared__ int sbase[NBT];
    __shared__ int cnt[VBK];
    __shared__ int wsum[4];
    if (blockIdx.x < NBV) {
        scan_gcnt(gCnt, sbase, wsum);
        int b = blockIdx.x;
        int id0 = b * VBK, nid = min(VBK, NN - id0);
        int start = sbase[NBE + b] - NNZP, end = start + gCnt[NBE + b];
        place_bucket_body(vbuckP, id0, nid, start, end, 16, 0xFFFFu, voff, elist, cnt, wsum);
        return;
    }
    int e = (blockIdx.x - NBV) * 16 + (threadIdx.x >> 4);
    if (e >= NE) return;
    int lane = threadIdx.x & 15;                 // covers cols [8*lane, 8*lane+8)
    int start = eoff[e], end = eoff[e + 1];
    float a[8] = {0.f, 0.f, 0.f, 0.f, 0.f, 0.f, 0.f, 0.f};
    int j = start;
    for (; j + 3 < end; j += 4) {
        int v0 = vlist[j], v1 = vlist[j + 1], v2 = vlist[j + 2], v3 = vlist[j + 3];
        u32x4 u0 = ldg_u4(Xp16 + (size_t)v0 * DD + lane * 8);
        u32x4 u1 = ldg_u4(Xp16 + (size_t)v1 * DD + lane * 8);
        u32x4 u2 = ldg_u4(Xp16 + (size_t)v2 * DD + lane * 8);
        u32x4 u3 = ldg_u4(Xp16 + (size_t)v3 * DD + lane * 8);
        accQ(u0, a); accQ(u1, a); accQ(u2, a); accQ(u3, a);
    }
    for (; j < end; ++j) {
        u32x4 u = ldg_u4(Xp16 + (size_t)vlist[j] * DD + lane * 8);
        accQ(u, a);
    }
    float inv = 1.0f / fmaxf((float)(end - start), 1.0f);
    f32x4 o0, o1;
    #pragma unroll
    for (int i = 0; i < 4; ++i) { o0[i] = a[i] * inv; o1[i] = a[4 + i] * inv; }
    float* xe = Xe + (size_t)e * DD + lane * 8;
    __builtin_nontemporal_store(o0, reinterpret_cast<f32x4*>(xe));
    __builtin_nontemporal_store(o1, reinterpret_cast<f32x4*>(xe + 4));
    ushort h[8];
    #pragma unroll
    for (int i = 0; i < 4; ++i) { h[i] = f2bf(o0[i]); h[4 + i] = f2bf(o1[i]); }
    *reinterpret_cast<int4*>(Xe16 + (size_t)e * DD + lane * 8) =
        *reinterpret_cast<const int4*>(h);       // re-read by K6: cached
}

// --- K6: Xv = sum Xe16 rows; out = normalize((1+eps)*Xp + Xv) (16-lane groups) ---
__global__ __launch_bounds__(256) void vertex_gather_out(const ushort* __restrict__ Xp16,
                                                         const ushort* __restrict__ Xe16,
                                                         const int* __restrict__ voff,
                                                         const int* __restrict__ elist,
                                                         const float* __restrict__ eps,
                                                         float* __restrict__ Out) {
    int v = blockIdx.x * 16 + (threadIdx.x >> 4);
    if (v >= NN) return;
    int lane = threadIdx.x & 15;
    int start = voff[v], end = voff[v + 1];
    float a[8] = {0.f, 0.f, 0.f, 0.f, 0.f, 0.f, 0.f, 0.f};
    int j = start;
    for (; j + 3 < end; j += 4) {
        int e0 = elist[j], e1 = elist[j + 1], e2 = elist[j + 2], e3 = elist[j + 3];
        u32x4 u0 = ldg_u4(Xe16 + (size_t)e0 * DD + lane * 8);
        u32x4 u1 = ldg_u4(Xe16 + (size_t)e1 * DD + lane * 8);
        u32x4 u2 = ldg_u4(Xe16 + (size_t)e2 * DD + lane * 8);
        u32x4 u3 = ldg_u4(Xe16 + (size_t)e3 * DD + lane * 8);
        accQ(u0, a); accQ(u1, a); accQ(u2, a); accQ(u3, a);
    }
    for (; j < end; ++j) {
        u32x4 u = ldg_u4(Xe16 + (size_t)elist[j] * DD + lane * 8);
        accQ(u, a);
    }
    float g = 1.0f + eps[0];
    u32x4 xp = __builtin_nontemporal_load(
        reinterpret_cast<const u32x4*>(Xp16 + (size_t)v * DD + lane * 8));  // sequential
    float o[8];
    o[0] = fmaf(g, __uint_as_float(xp.x << 16),         a[0]);
    o[1] = fmaf(g, __uint_as_float(xp.x & 0xffff0000u), a[1]);
    o[2] = fmaf(g, __uint_as_float(xp.y << 16),         a[2]);
    o[3] = fmaf(g, __uint_as_float(xp.y & 0xffff0000u), a[3]);
    o[4] = fmaf(g, __uint_as_float(xp.z << 16),         a[4]);
    o[5] = fmaf(g, __uint_as_float(xp.z & 0xffff0000u), a[5]);
    o[6] = fmaf(g, __uint_as_float(xp.w << 16),         a[6]);
    o[7] = fmaf(g, __uint_as_float(xp.w & 0xffff0000u), a[7]);
    float ss = 0.f;
    #pragma unroll
    for (int i = 0; i < 8; ++i) ss += o[i] * o[i];
    #pragma unroll
    for (int off = 1; off < 16; off <<= 1) ss += __shfl_xor(ss, off, 64);
    float inv = 1.0f / fmaxf(sqrtf(ss), 1e-12f);
    f32x4 s0, s1;
    #pragma unroll
    for (int i = 0; i < 4; ++i) { s0[i] = o[i] * inv; s1[i] = o[4 + i] * inv; }
    float* op = Out + (size_t)v * DD + lane * 8;
    __builtin_nontemporal_store(s0, reinterpret_cast<f32x4*>(op));
    __builtin_nontemporal_store(s1, reinterpret_cast<f32x4*>(op + 4));
}

extern "C" void kernel_launch(void* const* d_in, const int* in_sizes, int n_in,
                              void* d_out, int out_size, void* d_ws, size_t ws_size,
                              hipStream_t stream) {
    const float* X      = (const float*)d_in[0];
    const float* W      = (const float*)d_in[1];
    const float* eps    = (const float*)d_in[2];
    const int*   vertex = (const int*)d_in[3];
    const int*   edges  = (const int*)d_in[4];

    float* out = (float*)d_out;                 // [N,D] — scratch for buckets until K6
    float* Xe  = out + (size_t)NN * DD;         // [E,D]

    // packed bucket arrays live in the 'out' region (dead until vertex_gather_out)
    unsigned int* ebuckP = (unsigned int*)out;  // NNZ ints = 6.4 MB
    unsigned int* vbuckP = ebuckP + NNZP;       // NNZ ints = 6.4 MB (total 12.8 <= 51.2)

    // workspace layout (~52.5 MB)
    ushort* Xp16 = (ushort*)d_ws;                        // N*D bf16
    ushort* Xe16 = Xp16 + (size_t)NN * DD;               // E*D bf16
    ushort* Wt16 = Xe16 + (size_t)NE * DD;               // D*D bf16
    int*    eoff = (int*)(Wt16 + DD * DD);               // E+1
    int*    voff = eoff + NE + 1;                        // N+1
    int*    vlist = voff + NN + 1;                       // NNZ
    int*    elist = vlist + NNZP;                        // NNZ
    int*    gCnt  = elist + NNZP;                        // NBT
    int*    blkCnt = gCnt + NBT;                         // NBT*NSB = 147000

    scatter_count<<<NSB + 64, 256, 0, stream>>>(vertex, edges, blkCnt, W, Wt16);
    blk_scan<<<NBT, 256, 0, stream>>>(blkCnt, gCnt, eoff, voff);
    place_gemm<<<NGB + NSB, 256, 0, stream>>>(vertex, edges, blkCnt, gCnt,
                                              ebuckP, vbuckP, X, Wt16, Xp16);
    place_buckets_e<<<NBE, 256, 0, stream>>>(ebuckP, gCnt, eoff, vlist);
    edge_gather_pbv<<<NBV + NE / 16, 256, 0, stream>>>(Xp16, eoff, vlist, Xe, Xe16,
                                                       vbuckP, gCnt, voff, elist);
    vertex_gather_out<<<NN / 16, 256, 0, stream>>>(Xp16, Xe16, voff, elist, eps, out);
}

// Round 17
// 203.032 us; speedup vs baseline: 1.0628x; 1.0628x over previous
//
#include <hip/hip_runtime.h>
#include <hip/hip_bf16.h>

#define NN   100000
#define NE   50000
#define NNZP 1600000
#define DD   128

#define EBK  512
#define NBE  ((NE + EBK - 1) / EBK)             // 98
#define VBK  512
#define NBV  ((NN + VBK - 1) / VBK)             // 196
#define NBT  (NBE + NBV)                        // 294
#define CH2  1600                               // pairs per scatter block
#define NSB  1000                               // 1000 * 1600 == NNZP
#define NGB  ((NN / 16 + 7) / 8)                // 782 gemm blocks

typedef __attribute__((ext_vector_type(8))) short bf16x8;
typedef __attribute__((ext_vector_type(4))) float f32x4;
typedef __attribute__((ext_vector_type(4))) unsigned int u32x4;

__device__ __forceinline__ ushort f2bf(float f) {
    __hip_bfloat16 h = __float2bfloat16(f);
    return *reinterpret_cast<ushort*>(&h);
}
// accumulate 8 bf16 (one 16B load) into a[0..8)
__device__ __forceinline__ void accQ(u32x4 u, float* a) {
    a[0] += __uint_as_float(u.x << 16);
    a[1] += __uint_as_float(u.x & 0xffff0000u);
    a[2] += __uint_as_float(u.y << 16);
    a[3] += __uint_as_float(u.y & 0xffff0000u);
    a[4] += __uint_as_float(u.z << 16);
    a[5] += __uint_as_float(u.z & 0xffff0000u);
    a[6] += __uint_as_float(u.w << 16);
    a[7] += __uint_as_float(u.w & 0xffff0000u);
}
__device__ __forceinline__ u32x4 ldg_u4(const ushort* p) {
    return *reinterpret_cast<const u32x4*>(p);
}

// exclusive scan of gCnt[0..NBT) into sbase (LDS); 256 threads, 2 elems/thread
__device__ __forceinline__ void scan_gcnt(const int* __restrict__ gCnt,
                                          int* sbase, int* wsum) {
    const int t = threadIdx.x;
    int c0 = (2 * t     < NBT) ? gCnt[2 * t]     : 0;
    int c1 = (2 * t + 1 < NBT) ? gCnt[2 * t + 1] : 0;
    int s = c0 + c1;
    int inc = s;
    #pragma unroll
    for (int d = 1; d < 64; d <<= 1) {
        int x = __shfl_up(inc, d, 64);
        if ((t & 63) >= d) inc += x;
    }
    if ((t & 63) == 63) wsum[t >> 6] = inc;
    __syncthreads();
    int wid = t >> 6, wbase = 0;
    #pragma unroll
    for (int w = 0; w < 3; ++w) if (w < wid) wbase += wsum[w];
    int excl = wbase + inc - s;
    if (2 * t     < NBT) sbase[2 * t]     = excl;
    if (2 * t + 1 < NBT) sbase[2 * t + 1] = excl + c0;
    __syncthreads();
}

// ------- K1: per-(bucket,block) counts, no global atomics; + Wt convert tail -------
__global__ __launch_bounds__(256) void scatter_count(const int* __restrict__ vertex,
                                                     const int* __restrict__ edges,
                                                     int* __restrict__ blkCnt,
                                                     const float* __restrict__ W,
                                                     ushort* __restrict__ Wt) {
    __shared__ int c[NBT];
    const int t = threadIdx.x;
    if (blockIdx.x >= NSB) {        // tail: Wt16[n][k] = bf16(W[k][n])
        int i = (blockIdx.x - NSB) * 256 + t;
        if (i < DD * DD) { int k = i >> 7, n = i & 127; Wt[n * DD + k] = f2bf(W[i]); }
        return;
    }
    for (int i = t; i < NBT; i += 256) c[i] = 0;
    __syncthreads();
    const int base = blockIdx.x * CH2;
    for (int i = t; i < CH2 / 4; i += 256) {
        int4 e4 = *reinterpret_cast<const int4*>(edges + base + i * 4);
        int4 v4 = *reinterpret_cast<const int4*>(vertex + base + i * 4);
        atomicAdd(&c[e4.x >> 9], 1); atomicAdd(&c[e4.y >> 9], 1);
        atomicAdd(&c[e4.z >> 9], 1); atomicAdd(&c[e4.w >> 9], 1);
        atomicAdd(&c[NBE + (v4.x >> 9)], 1); atomicAdd(&c[NBE + (v4.y >> 9)], 1);
        atomicAdd(&c[NBE + (v4.z >> 9)], 1); atomicAdd(&c[NBE + (v4.w >> 9)], 1);
    }
    __syncthreads();
    for (int i = t; i < NBT; i += 256) blkCnt[i * NSB + blockIdx.x] = c[i];
}

// ------- K2: per-bucket scan of 1000 block counts -> relative offsets; total -> gCnt;
//             also writes the fixed CSR tails.  (4 elems/thread) -------
__global__ __launch_bounds__(256) void blk_scan(int* __restrict__ blkCnt,
                                                int* __restrict__ gCnt,
                                                int* __restrict__ eoff,
                                                int* __restrict__ voff) {
    __shared__ int wsum[4];
    const int t = threadIdx.x;
    if (blockIdx.x == 0 && t == 0) { eoff[NE] = NNZP; voff[NN] = NNZP; }
    int* p = blkCnt + blockIdx.x * NSB;
    int c0 = (4 * t     < NSB) ? p[4 * t]     : 0;
    int c1 = (4 * t + 1 < NSB) ? p[4 * t + 1] : 0;
    int c2 = (4 * t + 2 < NSB) ? p[4 * t + 2] : 0;
    int c3 = (4 * t + 3 < NSB) ? p[4 * t + 3] : 0;
    int s = c0 + c1 + c2 + c3;
    int inc = s;
    #pragma unroll
    for (int d = 1; d < 64; d <<= 1) {
        int x = __shfl_up(inc, d, 64);
        if ((t & 63) >= d) inc += x;
    }
    if ((t & 63) == 63) wsum[t >> 6] = inc;
    __syncthreads();
    int wid = t >> 6, wbase = 0;
    #pragma unroll
    for (int w = 0; w < 3; ++w) if (w < wid) wbase += wsum[w];
    int excl = wbase + inc - s;
    if (4 * t     < NSB) p[4 * t]     = excl;
    if (4 * t + 1 < NSB) p[4 * t + 1] = excl + c0;
    if (4 * t + 2 < NSB) p[4 * t + 2] = excl + c0 + c1;
    if (4 * t + 3 < NSB) p[4 * t + 3] = excl + c0 + c1 + c2;
    if (t == 255) gCnt[blockIdx.x] = wbase + inc;   // bucket total
}

// ------- K3 (fused): blocks [0,NGB) = MFMA GEMM; blocks [NGB,NGB+NSB) = placement ----
// ebuckP[i] = (e&511)<<17 | v ; vbuckP[i] = (v&511)<<16 | e
__global__ __launch_bounds__(256) void place_gemm(const int* __restrict__ vertex,
                                                  const int* __restrict__ edges,
                                                  const int* __restrict__ blkCnt,
                                                  const int* __restrict__ gCnt,
                                                  unsigned int* __restrict__ ebuckP,
                                                  unsigned int* __restrict__ vbuckP,
                                                  const float* __restrict__ X,
                                                  const ushort* __restrict__ Wt,
                                                  ushort* __restrict__ Xp16) {
    __shared__ char smem[DD * DD * 2];   // 32 KB: WtL (gemm) | sbase+cur (placement)
    __shared__ int wsum[4];
    const int t = threadIdx.x;
    if (blockIdx.x < NGB) {
        // ------- GEMM: Xp16 = bf16( X @ W ), 2 rowTiles/wave; Wt16 staged coalesced ----
        char* WtL = smem;
        for (int c = t; c < 2048; c += 256) {
            int n = c >> 4, kc = c & 15;
            int dst = (n * 256 + kc * 16) ^ ((n & 7) << 4);
            *reinterpret_cast<int4*>(WtL + dst) = reinterpret_cast<const int4*>(Wt)[c];
        }
        __syncthreads();
        int wave = t >> 6;
        int lane = t & 63;
        int r = lane & 15, half = lane >> 4;
        #pragma unroll
        for (int rt = 0; rt < 2; ++rt) {
            int rowTile = blockIdx.x * 8 + wave * 2 + rt;
            if (rowTile >= NN / 16) break;
            const float* xrow = X + (size_t)(rowTile * 16 + r) * DD;
            f32x4 acc[8];
            #pragma unroll
            for (int nt = 0; nt < 8; ++nt) acc[nt] = (f32x4)(0.f);
            #pragma unroll
            for (int kk = 0; kk < DD; kk += 32) {
                int kbase = kk + half * 8;
                float4 xa = *reinterpret_cast<const float4*>(xrow + kbase);
                float4 xb = *reinterpret_cast<const float4*>(xrow + kbase + 4);
                bf16x8 a;
                a[0] = (short)f2bf(xa.x); a[1] = (short)f2bf(xa.y);
                a[2] = (short)f2bf(xa.z); a[3] = (short)f2bf(xa.w);
                a[4] = (short)f2bf(xb.x); a[5] = (short)f2bf(xb.y);
                a[6] = (short)f2bf(xb.z); a[7] = (short)f2bf(xb.w);
                #pragma unroll
                for (int nt = 0; nt < 8; ++nt) {
                    int n = nt * 16 + r;
                    int off = (n * 256 + kbase * 2) ^ ((n & 7) << 4);
                    bf16x8 b = *reinterpret_cast<const bf16x8*>(WtL + off);
                    acc[nt] = __builtin_amdgcn_mfma_f32_16x16x32_bf16(a, b, acc[nt], 0, 0, 0);
                }
            }
            int row0 = rowTile * 16 + half * 4;   // C/D: col=lane&15, row=(lane>>4)*4+q
            #pragma unroll
            for (int nt = 0; nt < 8; ++nt)
                #pragma unroll
                for (int q = 0; q < 4; ++q)
                    Xp16[(size_t)(row0 + q) * DD + nt * 16 + r] = f2bf(acc[nt][q]);
        }
    } else {
        // ---------------- placement with deterministic cursors ----------------
        const int pb = blockIdx.x - NGB;          // 0..NSB-1
        int* sbase = reinterpret_cast<int*>(smem);       // NBT
        int* cur   = sbase + NBT;                        // NBT
        scan_gcnt(gCnt, sbase, wsum);
        for (int i = t; i < NBT; i += 256) {
            int rel = blkCnt[i * NSB + pb];
            int b = sbase[i] - ((i < NBE) ? 0 : NNZP);
            cur[i] = b + rel;
        }
        __syncthreads();
        const int base = pb * CH2;
        for (int i = t; i < CH2 / 2; i += 256) {
            int2 e2 = *reinterpret_cast<const int2*>(edges + base + i * 2);
            int2 v2 = *reinterpret_cast<const int2*>(vertex + base + i * 2);
            int pe0 = atomicAdd(&cur[e2.x >> 9], 1);
            ebuckP[pe0] = ((unsigned)(e2.x & 511) << 17) | (unsigned)v2.x;
            int pe1 = atomicAdd(&cur[e2.y >> 9], 1);
            ebuckP[pe1] = ((unsigned)(e2.y & 511) << 17) | (unsigned)v2.y;
            int pv0 = atomicAdd(&cur[NBE + (v2.x >> 9)], 1);
            vbuckP[pv0] = ((unsigned)(v2.x & 511) << 16) | (unsigned)e2.x;
            int pv1 = atomicAdd(&cur[NBE + (v2.y >> 9)], 1);
            vbuckP[pv1] = ((unsigned)(v2.y & 511) << 16) | (unsigned)e2.y;
        }
    }
}

// ------- K4: per bucket: LDS per-id hist + scan -> eoff/voff, then place ----
__global__ __launch_bounds__(256) void place_buckets2(const unsigned int* __restrict__ ebuckP,
                                                      const unsigned int* __restrict__ vbuckP,
                                                      const int* __restrict__ gCnt,
                                                      int* __restrict__ eoff,
                                                      int* __restrict__ voff,
                                                      int* __restrict__ vlist,
                                                      int* __restrict__ elist) {
    __shared__ int sbase[NBT];
    __shared__ int cnt[EBK];
    __shared__ int wsum[4];
    const int t = threadIdx.x;
    scan_gcnt(gCnt, sbase, wsum);
    int b = blockIdx.x;
    const unsigned int* buck; int id0, nid, start, end; int* off; int* lst;
    int sh_amt; unsigned msk;
    if (b < NBE) {
        buck = ebuckP; id0 = b * EBK; nid = min(EBK, NE - id0);
        start = sbase[b]; end = start + gCnt[b]; off = eoff; lst = vlist;
        sh_amt = 17; msk = 0x1FFFFu;
    } else {
        buck = vbuckP; id0 = (b - NBE) * VBK; nid = min(VBK, NN - id0);
        start = sbase[b] - NNZP; end = start + gCnt[b]; off = voff; lst = elist;
        sh_amt = 16; msk = 0xFFFFu;
    }
    for (int i = t; i < nid; i += 256) cnt[i] = 0;
    __syncthreads();
    for (int i = start + t; i < end; i += 256)
        atomicAdd(&cnt[buck[i] >> sh_amt], 1);
    __syncthreads();
    int c0 = (2 * t     < nid) ? cnt[2 * t]     : 0;
    int c1 = (2 * t + 1 < nid) ? cnt[2 * t + 1] : 0;
    int s = c0 + c1;
    int inc = s;
    #pragma unroll
    for (int d = 1; d < 64; d <<= 1) {
        int x = __shfl_up(inc, d, 64);
        if ((t & 63) >= d) inc += x;
    }
    if ((t & 63) == 63) wsum[t >> 6] = inc;
    __syncthreads();
    int wid = t >> 6, wbase = 0;
    #pragma unroll
    for (int w = 0; w < 3; ++w) if (w < wid) wbase += wsum[w];
    int excl = start + wbase + (inc - s);
    if (2 * t     < nid) off[id0 + 2 * t]     = excl;
    if (2 * t + 1 < nid) off[id0 + 2 * t + 1] = excl + c0;
    __syncthreads();
    if (2 * t     < nid) cnt[2 * t]     = excl;
    if (2 * t + 1 < nid) cnt[2 * t + 1] = excl + c0;
    __syncthreads();
    for (int i = start + t; i < end; i += 256) {
        unsigned p = buck[i];
        lst[atomicAdd(&cnt[p >> sh_amt], 1)] = (int)(p & msk);
    }
}

// ------ K5: Xe[e] = mean of Xp16 rows (16-lane groups, 16B loads, 4-deep) ------
__global__ __launch_bounds__(256) void edge_gather(const ushort* __restrict__ Xp16,
                                                   const int* __restrict__ eoff,
                                                   const int* __restrict__ vlist,
                                                   float* __restrict__ Xe,
                                                   ushort* __restrict__ Xe16) {
    int e = blockIdx.x * 16 + (threadIdx.x >> 4);
    if (e >= NE) return;
    int lane = threadIdx.x & 15;                 // covers cols [8*lane, 8*lane+8)
    int start = eoff[e], end = eoff[e + 1];
    float a[8] = {0.f, 0.f, 0.f, 0.f, 0.f, 0.f, 0.f, 0.f};
    int j = start;
    for (; j + 3 < end; j += 4) {
        int v0 = vlist[j], v1 = vlist[j + 1], v2 = vlist[j + 2], v3 = vlist[j + 3];
        u32x4 u0 = ldg_u4(Xp16 + (size_t)v0 * DD + lane * 8);
        u32x4 u1 = ldg_u4(Xp16 + (size_t)v1 * DD + lane * 8);
        u32x4 u2 = ldg_u4(Xp16 + (size_t)v2 * DD + lane * 8);
        u32x4 u3 = ldg_u4(Xp16 + (size_t)v3 * DD + lane * 8);
        accQ(u0, a); accQ(u1, a); accQ(u2, a); accQ(u3, a);
    }
    for (; j < end; ++j) {
        u32x4 u = ldg_u4(Xp16 + (size_t)vlist[j] * DD + lane * 8);
        accQ(u, a);
    }
    float inv = 1.0f / fmaxf((float)(end - start), 1.0f);
    f32x4 o0, o1;
    #pragma unroll
    for (int i = 0; i < 4; ++i) { o0[i] = a[i] * inv; o1[i] = a[4 + i] * inv; }
    float* xe = Xe + (size_t)e * DD + lane * 8;
    __builtin_nontemporal_store(o0, reinterpret_cast<f32x4*>(xe));
    __builtin_nontemporal_store(o1, reinterpret_cast<f32x4*>(xe + 4));
    ushort h[8];
    #pragma unroll
    for (int i = 0; i < 4; ++i) { h[i] = f2bf(o0[i]); h[4 + i] = f2bf(o1[i]); }
    *reinterpret_cast<int4*>(Xe16 + (size_t)e * DD + lane * 8) =
        *reinterpret_cast<const int4*>(h);       // re-read by K6: cached
}

// --- K6: Xv = sum Xe16 rows; out = normalize((1+eps)*Xp + Xv) (16-lane groups) ---
__global__ __launch_bounds__(256) void vertex_gather_out(const ushort* __restrict__ Xp16,
                                                         const ushort* __restrict__ Xe16,
                                                         const int* __restrict__ voff,
                                                         const int* __restrict__ elist,
                                                         const float* __restrict__ eps,
                                                         float* __restrict__ Out) {
    int v = blockIdx.x * 16 + (threadIdx.x >> 4);
    if (v >= NN) return;
    int lane = threadIdx.x & 15;
    int start = voff[v], end = voff[v + 1];
    float a[8] = {0.f, 0.f, 0.f, 0.f, 0.f, 0.f, 0.f, 0.f};
    int j = start;
    for (; j + 3 < end; j += 4) {
        int e0 = elist[j], e1 = elist[j + 1], e2 = elist[j + 2], e3 = elist[j + 3];
        u32x4 u0 = ldg_u4(Xe16 + (size_t)e0 * DD + lane * 8);
        u32x4 u1 = ldg_u4(Xe16 + (size_t)e1 * DD + lane * 8);
        u32x4 u2 = ldg_u4(Xe16 + (size_t)e2 * DD + lane * 8);
        u32x4 u3 = ldg_u4(Xe16 + (size_t)e3 * DD + lane * 8);
        accQ(u0, a); accQ(u1, a); accQ(u2, a); accQ(u3, a);
    }
    for (; j < end; ++j) {
        u32x4 u = ldg_u4(Xe16 + (size_t)elist[j] * DD + lane * 8);
        accQ(u, a);
    }
    float g = 1.0f + eps[0];
    u32x4 xp = __builtin_nontemporal_load(
        reinterpret_cast<const u32x4*>(Xp16 + (size_t)v * DD + lane * 8));  // sequential
    float o[8];
    o[0] = fmaf(g, __uint_as_float(xp.x << 16),         a[0]);
    o[1] = fmaf(g, __uint_as_float(xp.x & 0xffff0000u), a[1]);
    o[2] = fmaf(g, __uint_as_float(xp.y << 16),         a[2]);
    o[3] = fmaf(g, __uint_as_float(xp.y & 0xffff0000u), a[3]);
    o[4] = fmaf(g, __uint_as_float(xp.z << 16),         a[4]);
    o[5] = fmaf(g, __uint_as_float(xp.z & 0xffff0000u), a[5]);
    o[6] = fmaf(g, __uint_as_float(xp.w << 16),         a[6]);
    o[7] = fmaf(g, __uint_as_float(xp.w & 0xffff0000u), a[7]);
    float ss = 0.f;
    #pragma unroll
    for (int i = 0; i < 8; ++i) ss += o[i] * o[i];
    #pragma unroll
    for (int off = 1; off < 16; off <<= 1) ss += __shfl_xor(ss, off, 64);
    float inv = 1.0f / fmaxf(sqrtf(ss), 1e-12f);
    f32x4 s0, s1;
    #pragma unroll
    for (int i = 0; i < 4; ++i) { s0[i] = o[i] * inv; s1[i] = o[4 + i] * inv; }
    float* op = Out + (size_t)v * DD + lane * 8;
    __builtin_nontemporal_store(s0, reinterpret_cast<f32x4*>(op));
    __builtin_nontemporal_store(s1, reinterpret_cast<f32x4*>(op + 4));
}

extern "C" void kernel_launch(void* const* d_in, const int* in_sizes, int n_in,
                              void* d_out, int out_size, void* d_ws, size_t ws_size,
                              hipStream_t stream) {
    const float* X      = (const float*)d_in[0];
    const float* W      = (const float*)d_in[1];
    const float* eps    = (const float*)d_in[2];
    const int*   vertex = (const int*)d_in[3];
    const int*   edges  = (const int*)d_in[4];

    float* out = (float*)d_out;                 // [N,D] — scratch for buckets until K6
    float* Xe  = out + (size_t)NN * DD;         // [E,D]

    // packed bucket arrays live in the 'out' region (dead until vertex_gather_out)
    unsigned int* ebuckP = (unsigned int*)out;  // NNZ ints = 6.4 MB
    unsigned int* vbuckP = ebuckP + NNZP;       // NNZ ints = 6.4 MB (total 12.8 <= 51.2)

    // workspace layout (~53 MB)
    ushort* Xp16 = (ushort*)d_ws;                        // N*D bf16
    ushort* Xe16 = Xp16 + (size_t)NN * DD;               // E*D bf16
    ushort* Wt16 = Xe16 + (size_t)NE * DD;               // D*D bf16
    int*    eoff = (int*)(Wt16 + DD * DD);               // E+1
    int*    voff = eoff + NE + 1;                        // N+1
    int*    vlist = voff + NN + 1;                       // NNZ
    int*    elist = vlist + NNZP;                        // NNZ
    int*    gCnt  = elist + NNZP;                        // NBT
    int*    blkCnt = gCnt + NBT;                         // NBT*NSB = 294000

    scatter_count<<<NSB + 64, 256, 0, stream>>>(vertex, edges, blkCnt, W, Wt16);
    blk_scan<<<NBT, 256, 0, stream>>>(blkCnt, gCnt, eoff, voff);
    place_gemm<<<NGB + NSB, 256, 0, stream>>>(vertex, edges, blkCnt, gCnt,
                                              ebuckP, vbuckP, X, Wt16, Xp16);
    place_buckets2<<<NBT, 256, 0, stream>>>(ebuckP, vbuckP, gCnt, eoff, voff, vlist, elist);
    edge_gather<<<NE / 16, 256, 0, stream>>>(Xp16, eoff, vlist, Xe, Xe16);
    vertex_gather_out<<<NN / 16, 256, 0, stream>>>(Xp16, Xe16, voff, elist, eps, out);
}

// Round 18
// 194.239 us; speedup vs baseline: 1.1110x; 1.0453x over previous
//
#include <hip/hip_runtime.h>
#include <hip/hip_bf16.h>

#define NN   100000
#define NE   50000
#define NNZP 1600000
#define DD   128

#define EBK  512
#define NBE  ((NE + EBK - 1) / EBK)             // 98
#define VBK  512
#define NBV  ((NN + VBK - 1) / VBK)             // 196
#define NBT  (NBE + NBV)                        // 294
#define CH2  1600                               // pairs per scatter block
#define NSB  1000                               // 1000 * 1600 == NNZP
#define NGB  ((NN / 16 + 7) / 8)                // 782 gemm blocks

typedef __attribute__((ext_vector_type(8))) short bf16x8;
typedef __attribute__((ext_vector_type(4))) float f32x4;
typedef __attribute__((ext_vector_type(4))) unsigned int u32x4;

__device__ __forceinline__ ushort f2bf(float f) {
    __hip_bfloat16 h = __float2bfloat16(f);
    return *reinterpret_cast<ushort*>(&h);
}
// accumulate 8 bf16 (one 16B load) into a[0..8)
__device__ __forceinline__ void accQ(u32x4 u, float* a) {
    a[0] += __uint_as_float(u.x << 16);
    a[1] += __uint_as_float(u.x & 0xffff0000u);
    a[2] += __uint_as_float(u.y << 16);
    a[3] += __uint_as_float(u.y & 0xffff0000u);
    a[4] += __uint_as_float(u.z << 16);
    a[5] += __uint_as_float(u.z & 0xffff0000u);
    a[6] += __uint_as_float(u.w << 16);
    a[7] += __uint_as_float(u.w & 0xffff0000u);
}
__device__ __forceinline__ u32x4 ldg_u4(const ushort* p) {
    return *reinterpret_cast<const u32x4*>(p);
}

// exclusive scan of gCnt[0..NBT) into sbase (LDS); works for 256 or 512 threads
// (threads with 2*t >= NBT contribute 0; wsum[8] covers up to 8 waves)
__device__ __forceinline__ void scan_gcnt(const int* __restrict__ gCnt,
                                          int* sbase, int* wsum) {
    const int t = threadIdx.x;
    int c0 = (2 * t     < NBT) ? gCnt[2 * t]     : 0;
    int c1 = (2 * t + 1 < NBT) ? gCnt[2 * t + 1] : 0;
    int s = c0 + c1;
    int inc = s;
    #pragma unroll
    for (int d = 1; d < 64; d <<= 1) {
        int x = __shfl_up(inc, d, 64);
        if ((t & 63) >= d) inc += x;
    }
    if ((t & 63) == 63) wsum[t >> 6] = inc;
    __syncthreads();
    int wid = t >> 6, wbase = 0;
    #pragma unroll
    for (int w = 0; w < 7; ++w) if (w < wid) wbase += wsum[w];
    int excl = wbase + inc - s;
    if (2 * t     < NBT) sbase[2 * t]     = excl;
    if (2 * t + 1 < NBT) sbase[2 * t + 1] = excl + c0;
    __syncthreads();
}

// ------- K1: per-(block,bucket) counts, block-major blkCnt; + Wt convert tail -------
__global__ __launch_bounds__(256) void scatter_count(const int* __restrict__ vertex,
                                                     const int* __restrict__ edges,
                                                     int* __restrict__ blkCnt,
                                                     const float* __restrict__ W,
                                                     ushort* __restrict__ Wt) {
    __shared__ int c[NBT];
    const int t = threadIdx.x;
    if (blockIdx.x >= NSB) {        // tail: Wt16[n][k] = bf16(W[k][n])
        int i = (blockIdx.x - NSB) * 256 + t;
        if (i < DD * DD) { int k = i >> 7, n = i & 127; Wt[n * DD + k] = f2bf(W[i]); }
        return;
    }
    for (int i = t; i < NBT; i += 256) c[i] = 0;
    __syncthreads();
    const int base = blockIdx.x * CH2;
    for (int i = t; i < CH2 / 4; i += 256) {
        int4 e4 = *reinterpret_cast<const int4*>(edges + base + i * 4);
        int4 v4 = *reinterpret_cast<const int4*>(vertex + base + i * 4);
        atomicAdd(&c[e4.x >> 9], 1); atomicAdd(&c[e4.y >> 9], 1);
        atomicAdd(&c[e4.z >> 9], 1); atomicAdd(&c[e4.w >> 9], 1);
        atomicAdd(&c[NBE + (v4.x >> 9)], 1); atomicAdd(&c[NBE + (v4.y >> 9)], 1);
        atomicAdd(&c[NBE + (v4.z >> 9)], 1); atomicAdd(&c[NBE + (v4.w >> 9)], 1);
    }
    __syncthreads();
    for (int i = t; i < NBT; i += 256) blkCnt[blockIdx.x * NBT + i] = c[i];  // contiguous
}

// ------- K2: per-bucket scan of 1000 block counts (strided, block-major layout) ->
//             relative offsets in place; total -> gCnt; fixed CSR tails -------
#define BC(i) blkCnt[(size_t)(i) * NBT + blockIdx.x]
__global__ __launch_bounds__(256) void blk_scan(int* __restrict__ blkCnt,
                                                int* __restrict__ gCnt,
                                                int* __restrict__ eoff,
                                                int* __restrict__ voff) {
    __shared__ int wsum[8];
    const int t = threadIdx.x;
    if (blockIdx.x == 0 && t == 0) { eoff[NE] = NNZP; voff[NN] = NNZP; }
    int c0 = (4 * t     < NSB) ? BC(4 * t)     : 0;
    int c1 = (4 * t + 1 < NSB) ? BC(4 * t + 1) : 0;
    int c2 = (4 * t + 2 < NSB) ? BC(4 * t + 2) : 0;
    int c3 = (4 * t + 3 < NSB) ? BC(4 * t + 3) : 0;
    int s = c0 + c1 + c2 + c3;
    int inc = s;
    #pragma unroll
    for (int d = 1; d < 64; d <<= 1) {
        int x = __shfl_up(inc, d, 64);
        if ((t & 63) >= d) inc += x;
    }
    if ((t & 63) == 63) wsum[t >> 6] = inc;
    __syncthreads();
    int wid = t >> 6, wbase = 0;
    #pragma unroll
    for (int w = 0; w < 3; ++w) if (w < wid) wbase += wsum[w];
    int excl = wbase + inc - s;
    if (4 * t     < NSB) BC(4 * t)     = excl;
    if (4 * t + 1 < NSB) BC(4 * t + 1) = excl + c0;
    if (4 * t + 2 < NSB) BC(4 * t + 2) = excl + c0 + c1;
    if (4 * t + 3 < NSB) BC(4 * t + 3) = excl + c0 + c1 + c2;
    if (t == 255) gCnt[blockIdx.x] = wbase + inc;   // bucket total
}
#undef BC

// ------- K3 (fused): blocks [0,NGB) = MFMA GEMM; blocks [NGB,NGB+NSB) = placement ----
// ebuckP[i] = (e&511)<<17 | v ; vbuckP[i] = (v&511)<<16 | e
__global__ __launch_bounds__(256) void place_gemm(const int* __restrict__ vertex,
                                                  const int* __restrict__ edges,
                                                  const int* __restrict__ blkCnt,
                                                  const int* __restrict__ gCnt,
                                                  unsigned int* __restrict__ ebuckP,
                                                  unsigned int* __restrict__ vbuckP,
                                                  const float* __restrict__ X,
                                                  const ushort* __restrict__ Wt,
                                                  ushort* __restrict__ Xp16) {
    __shared__ char smem[DD * DD * 2];   // 32 KB: WtL (gemm) | sbase+cur (placement)
    __shared__ int wsum[8];
    const int t = threadIdx.x;
    if (blockIdx.x < NGB) {
        // ------- GEMM: Xp16 = bf16( X @ W ), 2 rowTiles/wave; Wt16 staged coalesced ----
        char* WtL = smem;
        for (int c = t; c < 2048; c += 256) {
            int n = c >> 4, kc = c & 15;
            int dst = (n * 256 + kc * 16) ^ ((n & 7) << 4);
            *reinterpret_cast<int4*>(WtL + dst) = reinterpret_cast<const int4*>(Wt)[c];
        }
        __syncthreads();
        int wave = t >> 6;
        int lane = t & 63;
        int r = lane & 15, half = lane >> 4;
        #pragma unroll
        for (int rt = 0; rt < 2; ++rt) {
            int rowTile = blockIdx.x * 8 + wave * 2 + rt;
            if (rowTile >= NN / 16) break;
            const float* xrow = X + (size_t)(rowTile * 16 + r) * DD;
            f32x4 acc[8];
            #pragma unroll
            for (int nt = 0; nt < 8; ++nt) acc[nt] = (f32x4)(0.f);
            #pragma unroll
            for (int kk = 0; kk < DD; kk += 32) {
                int kbase = kk + half * 8;
                float4 xa = *reinterpret_cast<const float4*>(xrow + kbase);
                float4 xb = *reinterpret_cast<const float4*>(xrow + kbase + 4);
                bf16x8 a;
                a[0] = (short)f2bf(xa.x); a[1] = (short)f2bf(xa.y);
                a[2] = (short)f2bf(xa.z); a[3] = (short)f2bf(xa.w);
                a[4] = (short)f2bf(xb.x); a[5] = (short)f2bf(xb.y);
                a[6] = (short)f2bf(xb.z); a[7] = (short)f2bf(xb.w);
                #pragma unroll
                for (int nt = 0; nt < 8; ++nt) {
                    int n = nt * 16 + r;
                    int off = (n * 256 + kbase * 2) ^ ((n & 7) << 4);
                    bf16x8 b = *reinterpret_cast<const bf16x8*>(WtL + off);
                    acc[nt] = __builtin_amdgcn_mfma_f32_16x16x32_bf16(a, b, acc[nt], 0, 0, 0);
                }
            }
            int row0 = rowTile * 16 + half * 4;   // C/D: col=lane&15, row=(lane>>4)*4+q
            #pragma unroll
            for (int nt = 0; nt < 8; ++nt)
                #pragma unroll
                for (int q = 0; q < 4; ++q)
                    Xp16[(size_t)(row0 + q) * DD + nt * 16 + r] = f2bf(acc[nt][q]);
        }
    } else {
        // ---------------- placement with deterministic cursors ----------------
        const int pb = blockIdx.x - NGB;          // 0..NSB-1
        int* sbase = reinterpret_cast<int*>(smem);       // NBT
        int* cur   = sbase + NBT;                        // NBT
        scan_gcnt(gCnt, sbase, wsum);
        for (int i = t; i < NBT; i += 256) {
            int rel = blkCnt[(size_t)pb * NBT + i];      // contiguous per block
            int b = sbase[i] - ((i < NBE) ? 0 : NNZP);
            cur[i] = b + rel;
        }
        __syncthreads();
        const int base = pb * CH2;
        for (int i = t; i < CH2 / 2; i += 256) {
            int2 e2 = *reinterpret_cast<const int2*>(edges + base + i * 2);
            int2 v2 = *reinterpret_cast<const int2*>(vertex + base + i * 2);
            int pe0 = atomicAdd(&cur[e2.x >> 9], 1);
            ebuckP[pe0] = ((unsigned)(e2.x & 511) << 17) | (unsigned)v2.x;
            int pe1 = atomicAdd(&cur[e2.y >> 9], 1);
            ebuckP[pe1] = ((unsigned)(e2.y & 511) << 17) | (unsigned)v2.y;
            int pv0 = atomicAdd(&cur[NBE + (v2.x >> 9)], 1);
            vbuckP[pv0] = ((unsigned)(v2.x & 511) << 16) | (unsigned)e2.x;
            int pv1 = atomicAdd(&cur[NBE + (v2.y >> 9)], 1);
            vbuckP[pv1] = ((unsigned)(v2.y & 511) << 16) | (unsigned)e2.y;
        }
    }
}

// ------- K4: per bucket (512 threads): LDS per-id hist + scan -> eoff/voff, place ----
__global__ __launch_bounds__(512) void place_buckets2(const unsigned int* __restrict__ ebuckP,
                                                      const unsigned int* __restrict__ vbuckP,
                                                      const int* __restrict__ gCnt,
                                                      int* __restrict__ eoff,
                                                      int* __restrict__ voff,
                                                      int* __restrict__ vlist,
                                                      int* __restrict__ elist) {
    __shared__ int sbase[NBT];
    __shared__ int cnt[EBK];
    __shared__ int wsum[8];
    const int t = threadIdx.x;
    scan_gcnt(gCnt, sbase, wsum);
    int b = blockIdx.x;
    const unsigned int* buck; int id0, nid, start, end; int* off; int* lst;
    int sh_amt; unsigned msk;
    if (b < NBE) {
        buck = ebuckP; id0 = b * EBK; nid = min(EBK, NE - id0);
        start = sbase[b]; end = start + gCnt[b]; off = eoff; lst = vlist;
        sh_amt = 17; msk = 0x1FFFFu;
    } else {
        buck = vbuckP; id0 = (b - NBE) * VBK; nid = min(VBK, NN - id0);
        start = sbase[b] - NNZP; end = start + gCnt[b]; off = voff; lst = elist;
        sh_amt = 16; msk = 0xFFFFu;
    }
    for (int i = t; i < nid; i += 512) cnt[i] = 0;
    __syncthreads();
    for (int i = start + t; i < end; i += 512)
        atomicAdd(&cnt[buck[i] >> sh_amt], 1);
    __syncthreads();
    int c0 = (2 * t     < nid) ? cnt[2 * t]     : 0;
    int c1 = (2 * t + 1 < nid) ? cnt[2 * t + 1] : 0;
    int s = c0 + c1;
    int inc = s;
    #pragma unroll
    for (int d = 1; d < 64; d <<= 1) {
        int x = __shfl_up(inc, d, 64);
        if ((t & 63) >= d) inc += x;
    }
    if ((t & 63) == 63) wsum[t >> 6] = inc;
    __syncthreads();
    int wid = t >> 6, wbase = 0;
    #pragma unroll
    for (int w = 0; w < 7; ++w) if (w < wid) wbase += wsum[w];
    int excl = start + wbase + (inc - s);
    if (2 * t     < nid) off[id0 + 2 * t]     = excl;
    if (2 * t + 1 < nid) off[id0 + 2 * t + 1] = excl + c0;
    __syncthreads();
    if (2 * t     < nid) cnt[2 * t]     = excl;
    if (2 * t + 1 < nid) cnt[2 * t + 1] = excl + c0;
    __syncthreads();
    for (int i = start + t; i < end; i += 512) {
        unsigned p = buck[i];
        lst[atomicAdd(&cnt[p >> sh_amt], 1)] = (int)(p & msk);
    }
}

// ------ K5: Xe[e] = mean of Xp16 rows (16-lane groups, 16B loads, 4-deep) ------
__global__ __launch_bounds__(256) void edge_gather(const ushort* __restrict__ Xp16,
                                                   const int* __restrict__ eoff,
                                                   const int* __restrict__ vlist,
                                                   float* __restrict__ Xe,
                                                   ushort* __restrict__ Xe16) {
    int e = blockIdx.x * 16 + (threadIdx.x >> 4);
    if (e >= NE) return;
    int lane = threadIdx.x & 15;                 // covers cols [8*lane, 8*lane+8)
    int start = eoff[e], end = eoff[e + 1];
    float a[8] = {0.f, 0.f, 0.f, 0.f, 0.f, 0.f, 0.f, 0.f};
    int j = start;
    for (; j + 3 < end; j += 4) {
        int v0 = vlist[j], v1 = vlist[j + 1], v2 = vlist[j + 2], v3 = vlist[j + 3];
        u32x4 u0 = ldg_u4(Xp16 + (size_t)v0 * DD + lane * 8);
        u32x4 u1 = ldg_u4(Xp16 + (size_t)v1 * DD + lane * 8);
        u32x4 u2 = ldg_u4(Xp16 + (size_t)v2 * DD + lane * 8);
        u32x4 u3 = ldg_u4(Xp16 + (size_t)v3 * DD + lane * 8);
        accQ(u0, a); accQ(u1, a); accQ(u2, a); accQ(u3, a);
    }
    for (; j < end; ++j) {
        u32x4 u = ldg_u4(Xp16 + (size_t)vlist[j] * DD + lane * 8);
        accQ(u, a);
    }
    float inv = 1.0f / fmaxf((float)(end - start), 1.0f);
    f32x4 o0, o1;
    #pragma unroll
    for (int i = 0; i < 4; ++i) { o0[i] = a[i] * inv; o1[i] = a[4 + i] * inv; }
    float* xe = Xe + (size_t)e * DD + lane * 8;
    __builtin_nontemporal_store(o0, reinterpret_cast<f32x4*>(xe));
    __builtin_nontemporal_store(o1, reinterpret_cast<f32x4*>(xe + 4));
    ushort h[8];
    #pragma unroll
    for (int i = 0; i < 4; ++i) { h[i] = f2bf(o0[i]); h[4 + i] = f2bf(o1[i]); }
    *reinterpret_cast<int4*>(Xe16 + (size_t)e * DD + lane * 8) =
        *reinterpret_cast<const int4*>(h);       // re-read by K6: cached
}

// --- K6: Xv = sum Xe16 rows; out = normalize((1+eps)*Xp + Xv) (16-lane groups) ---
__global__ __launch_bounds__(256) void vertex_gather_out(const ushort* __restrict__ Xp16,
                                                         const ushort* __restrict__ Xe16,
                                                         const int* __restrict__ voff,
                                                         const int* __restrict__ elist,
                                                         const float* __restrict__ eps,
                                                         float* __restrict__ Out) {
    int v = blockIdx.x * 16 + (threadIdx.x >> 4);
    if (v >= NN) return;
    int lane = threadIdx.x & 15;
    int start = voff[v], end = voff[v + 1];
    float a[8] = {0.f, 0.f, 0.f, 0.f, 0.f, 0.f, 0.f, 0.f};
    int j = start;
    for (; j + 3 < end; j += 4) {
        int e0 = elist[j], e1 = elist[j + 1], e2 = elist[j + 2], e3 = elist[j + 3];
        u32x4 u0 = ldg_u4(Xe16 + (size_t)e0 * DD + lane * 8);
        u32x4 u1 = ldg_u4(Xe16 + (size_t)e1 * DD + lane * 8);
        u32x4 u2 = ldg_u4(Xe16 + (size_t)e2 * DD + lane * 8);
        u32x4 u3 = ldg_u4(Xe16 + (size_t)e3 * DD + lane * 8);
        accQ(u0, a); accQ(u1, a); accQ(u2, a); accQ(u3, a);
    }
    for (; j < end; ++j) {
        u32x4 u = ldg_u4(Xe16 + (size_t)elist[j] * DD + lane * 8);
        accQ(u, a);
    }
    float g = 1.0f + eps[0];
    u32x4 xp = __builtin_nontemporal_load(
        reinterpret_cast<const u32x4*>(Xp16 + (size_t)v * DD + lane * 8));  // sequential
    float o[8];
    o[0] = fmaf(g, __uint_as_float(xp.x << 16),         a[0]);
    o[1] = fmaf(g, __uint_as_float(xp.x & 0xffff0000u), a[1]);
    o[2] = fmaf(g, __uint_as_float(xp.y << 16),         a[2]);
    o[3] = fmaf(g, __uint_as_float(xp.y & 0xffff0000u), a[3]);
    o[4] = fmaf(g, __uint_as_float(xp.z << 16),         a[4]);
    o[5] = fmaf(g, __uint_as_float(xp.z & 0xffff0000u), a[5]);
    o[6] = fmaf(g, __uint_as_float(xp.w << 16),         a[6]);
    o[7] = fmaf(g, __uint_as_float(xp.w & 0xffff0000u), a[7]);
    float ss = 0.f;
    #pragma unroll
    for (int i = 0; i < 8; ++i) ss += o[i] * o[i];
    #pragma unroll
    for (int off = 1; off < 16; off <<= 1) ss += __shfl_xor(ss, off, 64);
    float inv = 1.0f / fmaxf(sqrtf(ss), 1e-12f);
    f32x4 s0, s1;
    #pragma unroll
    for (int i = 0; i < 4; ++i) { s0[i] = o[i] * inv; s1[i] = o[4 + i] * inv; }
    float* op = Out + (size_t)v * DD + lane * 8;
    __builtin_nontemporal_store(s0, reinterpret_cast<f32x4*>(op));
    __builtin_nontemporal_store(s1, reinterpret_cast<f32x4*>(op + 4));
}

extern "C" void kernel_launch(void* const* d_in, const int* in_sizes, int n_in,
                              void* d_out, int out_size, void* d_ws, size_t ws_size,
                              hipStream_t stream) {
    const float* X      = (const float*)d_in[0];
    const float* W      = (const float*)d_in[1];
    const float* eps    = (const float*)d_in[2];
    const int*   vertex = (const int*)d_in[3];
    const int*   edges  = (const int*)d_in[4];

    float* out = (float*)d_out;                 // [N,D] — scratch for buckets until K6
    float* Xe  = out + (size_t)NN * DD;         // [E,D]

    // packed bucket arrays live in the 'out' region (dead until vertex_gather_out)
    unsigned int* ebuckP = (unsigned int*)out;  // NNZ ints = 6.4 MB
    unsigned int* vbuckP = ebuckP + NNZP;       // NNZ ints = 6.4 MB (total 12.8 <= 51.2)

    // workspace layout (~53 MB)
    ushort* Xp16 = (ushort*)d_ws;                        // N*D bf16
    ushort* Xe16 = Xp16 + (size_t)NN * DD;               // E*D bf16
    ushort* Wt16 = Xe16 + (size_t)NE * DD;               // D*D bf16
    int*    eoff = (int*)(Wt16 + DD * DD);               // E+1
    int*    voff = eoff + NE + 1;                        // N+1
    int*    vlist = voff + NN + 1;                       // NNZ
    int*    elist = vlist + NNZP;                        // NNZ
    int*    gCnt  = elist + NNZP;                        // NBT
    int*    blkCnt = gCnt + NBT;                         // NSB*NBT = 294000 (block-major)

    scatter_count<<<NSB + 64, 256, 0, stream>>>(vertex, edges, blkCnt, W, Wt16);
    blk_scan<<<NBT, 256, 0, stream>>>(blkCnt, gCnt, eoff, voff);
    place_gemm<<<NGB + NSB, 256, 0, stream>>>(vertex, edges, blkCnt, gCnt,
                                              ebuckP, vbuckP, X, Wt16, Xp16);
    place_buckets2<<<NBT, 512, 0, stream>>>(ebuckP, vbuckP, gCnt, eoff, voff, vlist, elist);
    edge_gather<<<NE / 16, 256, 0, stream>>>(Xp16, eoff, vlist, Xe, Xe16);
    vertex_gather_out<<<NN / 16, 256, 0, stream>>>(Xp16, Xe16, voff, elist, eps, out);
}